// Round 9
// baseline (236.727 us; speedup 1.0000x reference)
//
#include <hip/hip_runtime.h>

// LHGConv2d: transpose -> FCM (3 iters) -> top5 -> fused edge/cluster/linear.
// All f32 (harness inputs/outputs are float32).
// R3: k_m2 16-wave blocks (was 1 wave/SIMD latency-bound) 71us -> ~19us. VERIFIED.
// R5: k_m1/k_top5 cluster-sliced 8-wave blocks -> out of top-5. VERIFIED.
//     k_out 1024-thr REGRESSED (launch_bounds clamped VGPR 76->48 -> spills).
// R8: k_out back to 512-thr x 512 blocks: ~76 VGPR (no clamp), 2 blocks/CU
//     residency, same 16 waves/CU ceiling without the register starvation.

constexpr int B  = 4;
constexpr int C  = 64;
constexpr int N  = 8192;
constexpr int KE = 16;    // graph neighbors
constexpr int OC = 64;
constexpr int NC = 50;    // num_clusters
constexpr int TC = 5;     // top_clusters
constexpr int C3 = 192;   // 3*C
constexpr int NCP = 52;   // padded stride for um rows (13 float4)
constexpr int KG  = 5;    // clusters per k_m2 block
constexpr int NKG = 10;   // NC/KG
constexpr int NS  = 8;    // n-slices for deterministic partial reduction
constexpr int MW  = 16;   // waves per k_m2 block
constexpr float FEPS = 1e-8f;

// ---------------------------------------------------------------- transpose
// x (B,C,N) -> xt (B,N,C); also xn[b,n] = sum_c x^2 (for d2 expansion).
__global__ __launch_bounds__(256) void k_transpose(const float* __restrict__ x,
                                                   float* __restrict__ xt,
                                                   float* __restrict__ xn) {
  __shared__ float tile[64][65];           // +1 pad: conflict-free transpose
  int b  = blockIdx.x >> 7;                // 128 tiles per batch
  int n0 = (blockIdx.x & 127) << 6;
  int tid = threadIdx.x;
  int nl = tid & 63, cq = tid >> 6;
#pragma unroll
  for (int r = 0; r < 16; ++r) {
    int cc = r * 4 + cq;
    tile[cc][nl] = x[((size_t)b * C + cc) * N + n0 + nl];
  }
  __syncthreads();
  int cl = tid & 63, nq = tid >> 6;
#pragma unroll
  for (int r = 0; r < 16; ++r) {
    int nr = r * 4 + nq;
    xt[((size_t)b * N + n0 + nr) * C + cl] = tile[cl][nr];
  }
  if (tid < 64) {
    float s = 0.f;
#pragma unroll
    for (int cc = 0; cc < 64; ++cc) { float v = tile[cc][tid]; s = fmaf(v, v, s); }
    xn[(size_t)b * N + n0 + tid] = s;
  }
}

// ---------------------------------------------------------------- init cent
__global__ __launch_bounds__(256) void k_init(const float* __restrict__ xt,
                                              float* __restrict__ cent,
                                              float* __restrict__ cn) {
  int i = blockIdx.x * 256 + threadIdx.x;  // 0 .. B*NC*C-1 (12800)
  int lane = threadIdx.x & 63;
  int ccol = i & 63;
  int row  = i >> 6;                       // b*NC + k
  int k = row % NC, b = row / NC;
  int src = (k * (N - 1)) / (NC - 1);      // linspace().astype(int32)
  float v = xt[((size_t)b * N + src) * C + ccol];
  cent[i] = v;
  float sq = v * v;
#pragma unroll
  for (int off = 32; off; off >>= 1) sq += __shfl_down(sq, off, 64);
  if (lane == 0) cn[row] = sq;
}

// ---------------------------------------------------------------- membership
// R5: 512-thread blocks; 8 waves share 64 points, wave w computes a 6-7
// cluster slice (bases 0,7,14,20,26,32,38,44). Partial inv-sums combined in
// LDS (fixed order -> deterministic). 512 blocks * 8 waves = 16 waves/CU.
__global__ __launch_bounds__(512) void k_m1(const float* __restrict__ xt,
                                            const float* __restrict__ xn,
                                            const float* __restrict__ cent,
                                            const float* __restrict__ cn,
                                            float* __restrict__ um) {
  int gid = blockIdx.x;                    // 512 blocks
  int xcd = gid & 7;
  int b = xcd >> 1;                        // 2 XCDs per batch
  int chunk = ((gid >> 3) << 1) + (xcd & 1);  // 0..127
  int n0 = chunk << 6;                     // 64 points
  int w = __builtin_amdgcn_readfirstlane((int)threadIdx.x >> 6);  // 0..7
  int lane = threadIdx.x & 63;
  int n = n0 + lane;
  int base = (w < 2) ? 7 * w : 14 + 6 * (w - 2);
  int cnt  = (w < 2) ? 7 : 6;
  const float* xr = xt + ((size_t)b * N + n) * C;
  const float* cb = cent + b * NC * C;
  float dot[7];
#pragma unroll
  for (int j = 0; j < 7; ++j) dot[j] = 0.f;
  for (int c4 = 0; c4 < C; c4 += 4) {
    float4 xv = *(const float4*)(xr + c4);
#pragma unroll
    for (int j = 0; j < 7; ++j) {
      int kk = base + j; kk = (kk < NC) ? kk : 0;  // uniform clamp (wave 7, j=6)
      float4 cv = *(const float4*)(cb + kk * C + c4);  // uniform -> s_load
      dot[j] = fmaf(xv.x, cv.x, dot[j]);
      dot[j] = fmaf(xv.y, cv.y, dot[j]);
      dot[j] = fmaf(xv.z, cv.z, dot[j]);
      dot[j] = fmaf(xv.w, cv.w, dot[j]);
    }
  }
  float xnv = xn[(size_t)b * N + n];
  const float* cnb = cn + b * NC;
  float inv[7];
  float psum = 0.f;
#pragma unroll
  for (int j = 0; j < 7; ++j) {
    int kk = base + j; kk = (kk < NC) ? kk : 0;
    float d2 = fmaf(-2.f, dot[j], xnv + cnb[kk]);
    d2 = fmaxf(d2, FEPS);
    float iv = 1.f / d2;
    inv[j] = iv;
    psum += (j < cnt) ? iv : 0.f;
  }
  __shared__ float s_ps[8][64];
  s_ps[w][lane] = psum;
  __syncthreads();
  float ssum = 0.f;
#pragma unroll
  for (int ww = 0; ww < 8; ++ww) ssum += s_ps[ww][lane];  // fixed order
  float s2i = 1.f / (ssum * ssum);
  float* up = um + ((size_t)b * N + n) * NCP + base;
#pragma unroll
  for (int j = 0; j < 7; ++j)
    if (j < cnt) up[j] = inv[j] * inv[j] * s2i;
}

// ---------------------------------------------------------------- update GEMM
// partial[s][b][k][c] = sum_{n in slice s} um[n][k] * xt[n][c]  (deterministic)
__global__ __launch_bounds__(1024) void k_m2(const float* __restrict__ um,
                                             const float* __restrict__ xt,
                                             float* __restrict__ part_c,
                                             float* __restrict__ part_u) {
  int gid = blockIdx.x;                    // B*NKG*NS = 320
  int xcd = gid & 7;
  int b = xcd >> 1;
  int r = ((gid >> 3) << 1) + (xcd & 1);   // 0..79
  int kg = r >> 3;                         // 0..9
  int s  = r & 7;                          // 0..7
  int k0 = kg * KG;
  int w = __builtin_amdgcn_readfirstlane((int)threadIdx.x >> 6);  // wave 0..15
  int c = threadIdx.x & 63;
  int n0 = s * (N / NS);                   // 1024-point slice
  const float* umb = um + ((size_t)b * N + n0) * NCP + k0;
  const float* xb  = xt + ((size_t)b * N + n0) * C + c;
  float acc[KG], ua[KG];
#pragma unroll
  for (int j = 0; j < KG; ++j) { acc[j] = 0.f; ua[j] = 0.f; }
#pragma unroll 4
  for (int n = w; n < N / NS; n += MW) {   // 64 iterations
    float xv = xb[(size_t)n * C];
    const float* up = umb + (size_t)n * NCP;
#pragma unroll
    for (int j = 0; j < KG; ++j) {
      float u = up[j];                     // uniform -> s_load
      acc[j] = fmaf(u, xv, acc[j]);
      ua[j] += u;
    }
  }
  __shared__ float s_acc[MW][KG][64];      // 20 KiB
  __shared__ float s_ua[MW][KG];
#pragma unroll
  for (int j = 0; j < KG; ++j) s_acc[w][j][c] = acc[j];
  if (c == 0) {
#pragma unroll
    for (int j = 0; j < KG; ++j) s_ua[w][j] = ua[j];
  }
  __syncthreads();
  if (w == 0) {
#pragma unroll
    for (int j = 0; j < KG; ++j) {
      float t = 0.f;
#pragma unroll
      for (int ww = 0; ww < MW; ++ww) t += s_acc[ww][j][c];  // fixed order
      part_c[((size_t)s * (B * NC) + b * NC + k0 + j) * C + c] = t;
    }
    if (c == 0) {
#pragma unroll
      for (int j = 0; j < KG; ++j) {
        float t = 0.f;
#pragma unroll
        for (int ww = 0; ww < MW; ++ww) t += s_ua[ww][j];
        part_u[(size_t)s * (B * NC) + b * NC + k0 + j] = t;
      }
    }
  }
}

// ---------------------------------------------------------------- reduce+norm
__global__ __launch_bounds__(256) void k_m3(const float* __restrict__ part_c,
                                            const float* __restrict__ part_u,
                                            float* __restrict__ cent,
                                            float* __restrict__ cn) {
  int i = blockIdx.x * 256 + threadIdx.x;  // 12800
  int lane = threadIdx.x & 63;
  int row = i >> 6;
  float tot = 0.f;
#pragma unroll
  for (int s = 0; s < NS; ++s) tot += part_c[(size_t)s * (B * NC * C) + i];
  float us = 0.f;
#pragma unroll
  for (int s = 0; s < NS; ++s) us += part_u[(size_t)s * (B * NC) + row];
  float v = tot / (us + FEPS);
  cent[i] = v;
  float sq = v * v;
#pragma unroll
  for (int off = 32; off; off >>= 1) sq += __shfl_down(sq, off, 64);
  if (lane == 0) cn[row] = sq;
}

// ---------------------------------------------------------------- top-5
// R5: same 8-wave cluster-slice structure as k_m1; inv slices staged to LDS,
// wave 0 selects per point (ranking by inv == ranking by u; strict > keeps
// lowest index on ties, matching lax.top_k).
__global__ __launch_bounds__(512) void k_top5(const float* __restrict__ xt,
                                              const float* __restrict__ xn,
                                              const float* __restrict__ cent,
                                              const float* __restrict__ cn,
                                              int* __restrict__ t5) {
  int gid = blockIdx.x;                    // 512 blocks
  int xcd = gid & 7;
  int b = xcd >> 1;
  int chunk = ((gid >> 3) << 1) + (xcd & 1);  // 0..127
  int n0 = chunk << 6;
  int w = __builtin_amdgcn_readfirstlane((int)threadIdx.x >> 6);  // 0..7
  int lane = threadIdx.x & 63;
  int n = n0 + lane;
  int base = (w < 2) ? 7 * w : 14 + 6 * (w - 2);
  int cnt  = (w < 2) ? 7 : 6;
  const float* xr = xt + ((size_t)b * N + n) * C;
  const float* cb = cent + b * NC * C;
  float dot[7];
#pragma unroll
  for (int j = 0; j < 7; ++j) dot[j] = 0.f;
  for (int c4 = 0; c4 < C; c4 += 4) {
    float4 xv = *(const float4*)(xr + c4);
#pragma unroll
    for (int j = 0; j < 7; ++j) {
      int kk = base + j; kk = (kk < NC) ? kk : 0;
      float4 cv = *(const float4*)(cb + kk * C + c4);  // uniform -> s_load
      dot[j] = fmaf(xv.x, cv.x, dot[j]);
      dot[j] = fmaf(xv.y, cv.y, dot[j]);
      dot[j] = fmaf(xv.z, cv.z, dot[j]);
      dot[j] = fmaf(xv.w, cv.w, dot[j]);
    }
  }
  float xnv = xn[(size_t)b * N + n];
  const float* cnb = cn + b * NC;
  __shared__ float s_inv[NC][65];          // 13 KiB; [k][point]
#pragma unroll
  for (int j = 0; j < 7; ++j) {
    int kk = base + j; kk = (kk < NC) ? kk : 0;
    float d2 = fmaxf(fmaf(-2.f, dot[j], xnv + cnb[kk]), FEPS);
    float iv = 1.f / d2;
    if (j < cnt) s_inv[base + j][lane] = iv;
  }
  __syncthreads();
  if (w == 0) {
    float v[NC];
#pragma unroll
    for (int k = 0; k < NC; ++k) v[k] = s_inv[k][lane];  // conflict-free row read
    unsigned long long taken = 0ull;
    int* tp = t5 + ((size_t)b * N + n) * TC;
#pragma unroll
    for (int t = 0; t < TC; ++t) {
      float best = -1.f;
      int bi = 0;
#pragma unroll
      for (int k = 0; k < NC; ++k) {
        bool ok = (((taken >> k) & 1ull) == 0ull) && (v[k] > best);
        best = ok ? v[k] : best;
        bi   = ok ? k : bi;
      }
      taken |= (1ull << bi);
      tp[t] = bi;
    }
  }
}

// ---------------------------------------------------------------- fused output
// R8: 512-thr blocks (8 waves, 8 pts each), 512 blocks. No VGPR clamp (~76
// expected, 65-128 band -> 16 waves/CU; LDS 48.5KB -> 3-block cap; net 2
// blocks/CU resident). Phase A (lane=c): gathers; Phase B (lane=o): matvec
// with W from LDS per-lane and features broadcast via v_readlane.
__global__ __launch_bounds__(512) void k_out(const float* __restrict__ xt,
                                             const float* __restrict__ cent,
                                             const float* __restrict__ W,
                                             const int* __restrict__ t5,
                                             const int* __restrict__ eidx,
                                             const float* __restrict__ bias,
                                             float* __restrict__ out) {
  __shared__ float s_w[OC][C3 + 2];        // pad 194
  int tid = threadIdx.x;
  for (int i = tid; i < OC * C3; i += 512) {
    int o = i / C3, cc = i - o * C3;
    s_w[o][cc] = W[i];
  }
  __syncthreads();
  int gid = blockIdx.x;                    // 512 blocks
  int xcd = gid & 7;
  int b = xcd >> 1;
  int chunk = ((gid >> 3) << 1) + (xcd & 1);  // 0..127 (64 points each)
  int wv = __builtin_amdgcn_readfirstlane(tid >> 6);  // 0..7
  int lane = tid & 63;
  int n0 = chunk * 64 + wv * 8;
  const float* xtb = xt + ((size_t)b * N) * C;
  const float* cb  = cent + b * NC * C;
  const int* e0b = eidx + ((size_t)b * N) * KE;
  const int* e1b = eidx + ((size_t)(B + b) * N) * KE;
  int c = lane;
  float fA[8], fB[8], fC[8];
#pragma unroll
  for (int j = 0; j < 8; ++j) {
    int n = n0 + j;
    float x0 = xtb[(size_t)n * C + c];
    const int* p0 = e0b + (size_t)n * KE;  // uniform -> s_load
    const int* p1 = e1b + (size_t)n * KE;
    int i0v[KE], i1v[KE];
#pragma unroll
    for (int k = 0; k < KE; ++k) { i0v[k] = p0[k]; i1v[k] = p1[k]; }
    float m1 = 0.f;
#pragma unroll
    for (int k = 0; k < KE; ++k) {
      float d = xtb[(size_t)i0v[k] * C + c] - xtb[(size_t)i1v[k] * C + c];
      m1 = (k == 0) ? d : fmaxf(m1, d);
    }
    const int* tp = t5 + ((size_t)b * N + n) * TC;
    float cm = cb[(size_t)tp[0] * C + c];
#pragma unroll
    for (int t = 1; t < TC; ++t) cm = fmaxf(cm, cb[(size_t)tp[t] * C + c]);
    fA[j] = x0; fB[j] = m1; fC[j] = cm - x0;
  }
  float bo = bias[lane];
  float acc[8];
#pragma unroll
  for (int j = 0; j < 8; ++j) acc[j] = bo;
  for (int cp = 0; cp < 64; ++cp) {
    float w0 = s_w[lane][3 * cp + 0];
    float w1 = s_w[lane][3 * cp + 1];
    float w2 = s_w[lane][3 * cp + 2];
#pragma unroll
    for (int j = 0; j < 8; ++j) {
      float a0 = __uint_as_float(__builtin_amdgcn_readlane(__float_as_uint(fA[j]), cp));
      float a1 = __uint_as_float(__builtin_amdgcn_readlane(__float_as_uint(fB[j]), cp));
      float a2 = __uint_as_float(__builtin_amdgcn_readlane(__float_as_uint(fC[j]), cp));
      acc[j] = fmaf(w0, a0, acc[j]);
      acc[j] = fmaf(w1, a1, acc[j]);
      acc[j] = fmaf(w2, a2, acc[j]);
    }
  }
  float* op = out + ((size_t)b * OC + lane) * N + n0;
  *(float4*)(op)     = make_float4(fmaxf(acc[0], 0.f), fmaxf(acc[1], 0.f),
                                   fmaxf(acc[2], 0.f), fmaxf(acc[3], 0.f));
  *(float4*)(op + 4) = make_float4(fmaxf(acc[4], 0.f), fmaxf(acc[5], 0.f),
                                   fmaxf(acc[6], 0.f), fmaxf(acc[7], 0.f));
}

// ----------------------------------------------------------------------------
extern "C" void kernel_launch(void* const* d_in, const int* in_sizes, int n_in,
                              void* d_out, int out_size, void* d_ws, size_t ws_size,
                              hipStream_t stream) {
  const float* x    = (const float*)d_in[0];
  const int*   eidx = (const int*)d_in[1];
  const float* W    = (const float*)d_in[2];
  const float* bias = (const float*)d_in[3];

  float* ws   = (float*)d_ws;
  float* xt   = ws;                          // B*N*C       = 2,097,152
  float* xn   = xt + (size_t)B * N * C;      // B*N         =    32,768
  float* cent = xn + (size_t)B * N;          // B*NC*C      =    12,800
  float* cn   = cent + B * NC * C;           // 256 (200 used)
  float* um   = cn + 256;                    // B*N*NCP     = 1,703,936
  float* pc   = um + (size_t)B * N * NCP;    // NS*B*NC*C   =   102,400
  float* pu   = pc + (size_t)NS * B * NC * C;// NS*B*NC     =     1,600
  int*   t5   = (int*)(pu + NS * B * NC);    // B*N*TC ints =   163,840
  float* out  = (float*)d_out;               // total ws ~16.46 MB (unchanged)

  k_transpose<<<dim3(B * (N / 64)), dim3(256), 0, stream>>>(x, xt, xn);
  k_init<<<dim3((B * NC * C) / 256), dim3(256), 0, stream>>>(xt, cent, cn);
  for (int it = 0; it < 3; ++it) {
    k_m1<<<dim3(512), dim3(512), 0, stream>>>(xt, xn, cent, cn, um);
    k_m2<<<dim3(B * NKG * NS), dim3(1024), 0, stream>>>(um, xt, pc, pu);
    k_m3<<<dim3((B * NC * C) / 256), dim3(256), 0, stream>>>(pc, pu, cent, cn);
  }
  k_top5<<<dim3(512), dim3(512), 0, stream>>>(xt, xn, cent, cn, t5);
  k_out<<<dim3(512), dim3(512), 0, stream>>>(xt, cent, W, t5, eidx, bias, out);
}

// Round 10
// 228.364 us; speedup vs baseline: 1.0366x; 1.0366x over previous
//
#include <hip/hip_runtime.h>

// LHGConv2d: transpose -> FCM (3 iters) -> top5 -> fused edge/cluster/linear.
// All f32 (harness inputs/outputs are float32).
// R3: k_m2 16-wave blocks 71us -> ~19us. VERIFIED.
// R5: k_m1/k_top5 cluster-sliced 8-wave blocks -> out of top-5. VERIFIED.
// R8: k_out VGPR theory falsified: compiler chose 40 VGPR voluntarily ->
//     gather loads serialized (can't keep 38 loads/point in flight).
// R9: k_out __launch_bounds__(512,4) (128-VGPR budget) + explicit
//     load-all-then-consume gather batches to force deep VMEM pipelining.

constexpr int B  = 4;
constexpr int C  = 64;
constexpr int N  = 8192;
constexpr int KE = 16;    // graph neighbors
constexpr int OC = 64;
constexpr int NC = 50;    // num_clusters
constexpr int TC = 5;     // top_clusters
constexpr int C3 = 192;   // 3*C
constexpr int NCP = 52;   // padded stride for um rows (13 float4)
constexpr int KG  = 5;    // clusters per k_m2 block
constexpr int NKG = 10;   // NC/KG
constexpr int NS  = 8;    // n-slices for deterministic partial reduction
constexpr int MW  = 16;   // waves per k_m2 block
constexpr float FEPS = 1e-8f;

// ---------------------------------------------------------------- transpose
__global__ __launch_bounds__(256) void k_transpose(const float* __restrict__ x,
                                                   float* __restrict__ xt,
                                                   float* __restrict__ xn) {
  __shared__ float tile[64][65];           // +1 pad: conflict-free transpose
  int b  = blockIdx.x >> 7;                // 128 tiles per batch
  int n0 = (blockIdx.x & 127) << 6;
  int tid = threadIdx.x;
  int nl = tid & 63, cq = tid >> 6;
#pragma unroll
  for (int r = 0; r < 16; ++r) {
    int cc = r * 4 + cq;
    tile[cc][nl] = x[((size_t)b * C + cc) * N + n0 + nl];
  }
  __syncthreads();
  int cl = tid & 63, nq = tid >> 6;
#pragma unroll
  for (int r = 0; r < 16; ++r) {
    int nr = r * 4 + nq;
    xt[((size_t)b * N + n0 + nr) * C + cl] = tile[cl][nr];
  }
  if (tid < 64) {
    float s = 0.f;
#pragma unroll
    for (int cc = 0; cc < 64; ++cc) { float v = tile[cc][tid]; s = fmaf(v, v, s); }
    xn[(size_t)b * N + n0 + tid] = s;
  }
}

// ---------------------------------------------------------------- init cent
__global__ __launch_bounds__(256) void k_init(const float* __restrict__ xt,
                                              float* __restrict__ cent,
                                              float* __restrict__ cn) {
  int i = blockIdx.x * 256 + threadIdx.x;  // 0 .. B*NC*C-1 (12800)
  int lane = threadIdx.x & 63;
  int ccol = i & 63;
  int row  = i >> 6;                       // b*NC + k
  int k = row % NC, b = row / NC;
  int src = (k * (N - 1)) / (NC - 1);      // linspace().astype(int32)
  float v = xt[((size_t)b * N + src) * C + ccol];
  cent[i] = v;
  float sq = v * v;
#pragma unroll
  for (int off = 32; off; off >>= 1) sq += __shfl_down(sq, off, 64);
  if (lane == 0) cn[row] = sq;
}

// ---------------------------------------------------------------- membership
__global__ __launch_bounds__(512) void k_m1(const float* __restrict__ xt,
                                            const float* __restrict__ xn,
                                            const float* __restrict__ cent,
                                            const float* __restrict__ cn,
                                            float* __restrict__ um) {
  int gid = blockIdx.x;                    // 512 blocks
  int xcd = gid & 7;
  int b = xcd >> 1;                        // 2 XCDs per batch
  int chunk = ((gid >> 3) << 1) + (xcd & 1);  // 0..127
  int n0 = chunk << 6;                     // 64 points
  int w = __builtin_amdgcn_readfirstlane((int)threadIdx.x >> 6);  // 0..7
  int lane = threadIdx.x & 63;
  int n = n0 + lane;
  int base = (w < 2) ? 7 * w : 14 + 6 * (w - 2);
  int cnt  = (w < 2) ? 7 : 6;
  const float* xr = xt + ((size_t)b * N + n) * C;
  const float* cb = cent + b * NC * C;
  float dot[7];
#pragma unroll
  for (int j = 0; j < 7; ++j) dot[j] = 0.f;
  for (int c4 = 0; c4 < C; c4 += 4) {
    float4 xv = *(const float4*)(xr + c4);
#pragma unroll
    for (int j = 0; j < 7; ++j) {
      int kk = base + j; kk = (kk < NC) ? kk : 0;  // uniform clamp (wave 7, j=6)
      float4 cv = *(const float4*)(cb + kk * C + c4);  // uniform -> s_load
      dot[j] = fmaf(xv.x, cv.x, dot[j]);
      dot[j] = fmaf(xv.y, cv.y, dot[j]);
      dot[j] = fmaf(xv.z, cv.z, dot[j]);
      dot[j] = fmaf(xv.w, cv.w, dot[j]);
    }
  }
  float xnv = xn[(size_t)b * N + n];
  const float* cnb = cn + b * NC;
  float inv[7];
  float psum = 0.f;
#pragma unroll
  for (int j = 0; j < 7; ++j) {
    int kk = base + j; kk = (kk < NC) ? kk : 0;
    float d2 = fmaf(-2.f, dot[j], xnv + cnb[kk]);
    d2 = fmaxf(d2, FEPS);
    float iv = 1.f / d2;
    inv[j] = iv;
    psum += (j < cnt) ? iv : 0.f;
  }
  __shared__ float s_ps[8][64];
  s_ps[w][lane] = psum;
  __syncthreads();
  float ssum = 0.f;
#pragma unroll
  for (int ww = 0; ww < 8; ++ww) ssum += s_ps[ww][lane];  // fixed order
  float s2i = 1.f / (ssum * ssum);
  float* up = um + ((size_t)b * N + n) * NCP + base;
#pragma unroll
  for (int j = 0; j < 7; ++j)
    if (j < cnt) up[j] = inv[j] * inv[j] * s2i;
}

// ---------------------------------------------------------------- update GEMM
__global__ __launch_bounds__(1024) void k_m2(const float* __restrict__ um,
                                             const float* __restrict__ xt,
                                             float* __restrict__ part_c,
                                             float* __restrict__ part_u) {
  int gid = blockIdx.x;                    // B*NKG*NS = 320
  int xcd = gid & 7;
  int b = xcd >> 1;
  int r = ((gid >> 3) << 1) + (xcd & 1);   // 0..79
  int kg = r >> 3;                         // 0..9
  int s  = r & 7;                          // 0..7
  int k0 = kg * KG;
  int w = __builtin_amdgcn_readfirstlane((int)threadIdx.x >> 6);  // wave 0..15
  int c = threadIdx.x & 63;
  int n0 = s * (N / NS);                   // 1024-point slice
  const float* umb = um + ((size_t)b * N + n0) * NCP + k0;
  const float* xb  = xt + ((size_t)b * N + n0) * C + c;
  float acc[KG], ua[KG];
#pragma unroll
  for (int j = 0; j < KG; ++j) { acc[j] = 0.f; ua[j] = 0.f; }
#pragma unroll 4
  for (int n = w; n < N / NS; n += MW) {   // 64 iterations
    float xv = xb[(size_t)n * C];
    const float* up = umb + (size_t)n * NCP;
#pragma unroll
    for (int j = 0; j < KG; ++j) {
      float u = up[j];                     // uniform -> s_load
      acc[j] = fmaf(u, xv, acc[j]);
      ua[j] += u;
    }
  }
  __shared__ float s_acc[MW][KG][64];      // 20 KiB
  __shared__ float s_ua[MW][KG];
#pragma unroll
  for (int j = 0; j < KG; ++j) s_acc[w][j][c] = acc[j];
  if (c == 0) {
#pragma unroll
    for (int j = 0; j < KG; ++j) s_ua[w][j] = ua[j];
  }
  __syncthreads();
  if (w == 0) {
#pragma unroll
    for (int j = 0; j < KG; ++j) {
      float t = 0.f;
#pragma unroll
      for (int ww = 0; ww < MW; ++ww) t += s_acc[ww][j][c];  // fixed order
      part_c[((size_t)s * (B * NC) + b * NC + k0 + j) * C + c] = t;
    }
    if (c == 0) {
#pragma unroll
      for (int j = 0; j < KG; ++j) {
        float t = 0.f;
#pragma unroll
        for (int ww = 0; ww < MW; ++ww) t += s_ua[ww][j];
        part_u[(size_t)s * (B * NC) + b * NC + k0 + j] = t;
      }
    }
  }
}

// ---------------------------------------------------------------- reduce+norm
__global__ __launch_bounds__(256) void k_m3(const float* __restrict__ part_c,
                                            const float* __restrict__ part_u,
                                            float* __restrict__ cent,
                                            float* __restrict__ cn) {
  int i = blockIdx.x * 256 + threadIdx.x;  // 12800
  int lane = threadIdx.x & 63;
  int row = i >> 6;
  float tot = 0.f;
#pragma unroll
  for (int s = 0; s < NS; ++s) tot += part_c[(size_t)s * (B * NC * C) + i];
  float us = 0.f;
#pragma unroll
  for (int s = 0; s < NS; ++s) us += part_u[(size_t)s * (B * NC) + row];
  float v = tot / (us + FEPS);
  cent[i] = v;
  float sq = v * v;
#pragma unroll
  for (int off = 32; off; off >>= 1) sq += __shfl_down(sq, off, 64);
  if (lane == 0) cn[row] = sq;
}

// ---------------------------------------------------------------- top-5
__global__ __launch_bounds__(512) void k_top5(const float* __restrict__ xt,
                                              const float* __restrict__ xn,
                                              const float* __restrict__ cent,
                                              const float* __restrict__ cn,
                                              int* __restrict__ t5) {
  int gid = blockIdx.x;                    // 512 blocks
  int xcd = gid & 7;
  int b = xcd >> 1;
  int chunk = ((gid >> 3) << 1) + (xcd & 1);  // 0..127
  int n0 = chunk << 6;
  int w = __builtin_amdgcn_readfirstlane((int)threadIdx.x >> 6);  // 0..7
  int lane = threadIdx.x & 63;
  int n = n0 + lane;
  int base = (w < 2) ? 7 * w : 14 + 6 * (w - 2);
  int cnt  = (w < 2) ? 7 : 6;
  const float* xr = xt + ((size_t)b * N + n) * C;
  const float* cb = cent + b * NC * C;
  float dot[7];
#pragma unroll
  for (int j = 0; j < 7; ++j) dot[j] = 0.f;
  for (int c4 = 0; c4 < C; c4 += 4) {
    float4 xv = *(const float4*)(xr + c4);
#pragma unroll
    for (int j = 0; j < 7; ++j) {
      int kk = base + j; kk = (kk < NC) ? kk : 0;
      float4 cv = *(const float4*)(cb + kk * C + c4);  // uniform -> s_load
      dot[j] = fmaf(xv.x, cv.x, dot[j]);
      dot[j] = fmaf(xv.y, cv.y, dot[j]);
      dot[j] = fmaf(xv.z, cv.z, dot[j]);
      dot[j] = fmaf(xv.w, cv.w, dot[j]);
    }
  }
  float xnv = xn[(size_t)b * N + n];
  const float* cnb = cn + b * NC;
  __shared__ float s_inv[NC][65];          // 13 KiB; [k][point]
#pragma unroll
  for (int j = 0; j < 7; ++j) {
    int kk = base + j; kk = (kk < NC) ? kk : 0;
    float d2 = fmaxf(fmaf(-2.f, dot[j], xnv + cnb[kk]), FEPS);
    float iv = 1.f / d2;
    if (j < cnt) s_inv[base + j][lane] = iv;
  }
  __syncthreads();
  if (w == 0) {
    float v[NC];
#pragma unroll
    for (int k = 0; k < NC; ++k) v[k] = s_inv[k][lane];  // conflict-free row read
    unsigned long long taken = 0ull;
    int* tp = t5 + ((size_t)b * N + n) * TC;
#pragma unroll
    for (int t = 0; t < TC; ++t) {
      float best = -1.f;
      int bi = 0;
#pragma unroll
      for (int k = 0; k < NC; ++k) {
        bool ok = (((taken >> k) & 1ull) == 0ull) && (v[k] > best);
        best = ok ? v[k] : best;
        bi   = ok ? k : bi;
      }
      taken |= (1ull << bi);
      tp[t] = bi;
    }
  }
}

// ---------------------------------------------------------------- fused output
// R9: (512,4) = 4 waves/SIMD declared -> 128-VGPR budget (compiler chose 40
// on its own in R8, serializing the 38 gathers/point). Phase A loads are now
// batched into explicit arrays (g0/g1/cv live simultaneously) so the compiler
// must issue them back-to-back and wait once per point. fmax chain order
// unchanged -> bit-identical output.
__global__ __launch_bounds__(512, 4) void k_out(const float* __restrict__ xt,
                                                const float* __restrict__ cent,
                                                const float* __restrict__ W,
                                                const int* __restrict__ t5,
                                                const int* __restrict__ eidx,
                                                const float* __restrict__ bias,
                                                float* __restrict__ out) {
  __shared__ float s_w[OC][C3 + 2];        // pad 194
  int tid = threadIdx.x;
  for (int i = tid; i < OC * C3; i += 512) {
    int o = i / C3, cc = i - o * C3;
    s_w[o][cc] = W[i];
  }
  __syncthreads();
  int gid = blockIdx.x;                    // 512 blocks
  int xcd = gid & 7;
  int b = xcd >> 1;
  int chunk = ((gid >> 3) << 1) + (xcd & 1);  // 0..127 (64 points each)
  int wv = __builtin_amdgcn_readfirstlane(tid >> 6);  // 0..7
  int lane = tid & 63;
  int n0 = chunk * 64 + wv * 8;
  const float* xtb = xt + ((size_t)b * N) * C;
  const float* cb  = cent + b * NC * C;
  const int* e0b = eidx + ((size_t)b * N) * KE;
  const int* e1b = eidx + ((size_t)(B + b) * N) * KE;
  int c = lane;
  float fA[8], fB[8], fC[8];
#pragma unroll
  for (int j = 0; j < 8; ++j) {
    int n = n0 + j;
    const int* p0 = e0b + (size_t)n * KE;  // uniform -> s_load
    const int* p1 = e1b + (size_t)n * KE;
    const int* tp = t5 + ((size_t)b * N + n) * TC;
    // ---- issue ALL loads for this point first (38 live results) ----
    float x0 = xtb[(size_t)n * C + c];
    float g0[KE], g1[KE];
#pragma unroll
    for (int k = 0; k < KE; ++k) {
      g0[k] = xtb[(size_t)p0[k] * C + c];
      g1[k] = xtb[(size_t)p1[k] * C + c];
    }
    float cv[TC];
#pragma unroll
    for (int t = 0; t < TC; ++t) cv[t] = cb[(size_t)tp[t] * C + c];
    // ---- consume (same fmax order as before -> bit-identical) ----
    float m1 = g0[0] - g1[0];
#pragma unroll
    for (int k = 1; k < KE; ++k) m1 = fmaxf(m1, g0[k] - g1[k]);
    float cm = cv[0];
#pragma unroll
    for (int t = 1; t < TC; ++t) cm = fmaxf(cm, cv[t]);
    fA[j] = x0; fB[j] = m1; fC[j] = cm - x0;
  }
  float bo = bias[lane];
  float acc[8];
#pragma unroll
  for (int j = 0; j < 8; ++j) acc[j] = bo;
  for (int cp = 0; cp < 64; ++cp) {
    float w0 = s_w[lane][3 * cp + 0];
    float w1 = s_w[lane][3 * cp + 1];
    float w2 = s_w[lane][3 * cp + 2];
#pragma unroll
    for (int j = 0; j < 8; ++j) {
      float a0 = __uint_as_float(__builtin_amdgcn_readlane(__float_as_uint(fA[j]), cp));
      float a1 = __uint_as_float(__builtin_amdgcn_readlane(__float_as_uint(fB[j]), cp));
      float a2 = __uint_as_float(__builtin_amdgcn_readlane(__float_as_uint(fC[j]), cp));
      acc[j] = fmaf(w0, a0, acc[j]);
      acc[j] = fmaf(w1, a1, acc[j]);
      acc[j] = fmaf(w2, a2, acc[j]);
    }
  }
  float* op = out + ((size_t)b * OC + lane) * N + n0;
  *(float4*)(op)     = make_float4(fmaxf(acc[0], 0.f), fmaxf(acc[1], 0.f),
                                   fmaxf(acc[2], 0.f), fmaxf(acc[3], 0.f));
  *(float4*)(op + 4) = make_float4(fmaxf(acc[4], 0.f), fmaxf(acc[5], 0.f),
                                   fmaxf(acc[6], 0.f), fmaxf(acc[7], 0.f));
}

// ----------------------------------------------------------------------------
extern "C" void kernel_launch(void* const* d_in, const int* in_sizes, int n_in,
                              void* d_out, int out_size, void* d_ws, size_t ws_size,
                              hipStream_t stream) {
  const float* x    = (const float*)d_in[0];
  const int*   eidx = (const int*)d_in[1];
  const float* W    = (const float*)d_in[2];
  const float* bias = (const float*)d_in[3];

  float* ws   = (float*)d_ws;
  float* xt   = ws;                          // B*N*C       = 2,097,152
  float* xn   = xt + (size_t)B * N * C;      // B*N         =    32,768
  float* cent = xn + (size_t)B * N;          // B*NC*C      =    12,800
  float* cn   = cent + B * NC * C;           // 256 (200 used)
  float* um   = cn + 256;                    // B*N*NCP     = 1,703,936
  float* pc   = um + (size_t)B * N * NCP;    // NS*B*NC*C   =   102,400
  float* pu   = pc + (size_t)NS * B * NC * C;// NS*B*NC     =     1,600
  int*   t5   = (int*)(pu + NS * B * NC);    // B*N*TC ints =   163,840
  float* out  = (float*)d_out;               // total ws ~16.46 MB (unchanged)

  k_transpose<<<dim3(B * (N / 64)), dim3(256), 0, stream>>>(x, xt, xn);
  k_init<<<dim3((B * NC * C) / 256), dim3(256), 0, stream>>>(xt, cent, cn);
  for (int it = 0; it < 3; ++it) {
    k_m1<<<dim3(512), dim3(512), 0, stream>>>(xt, xn, cent, cn, um);
    k_m2<<<dim3(B * NKG * NS), dim3(1024), 0, stream>>>(um, xt, pc, pu);
    k_m3<<<dim3((B * NC * C) / 256), dim3(256), 0, stream>>>(pc, pu, cent, cn);
  }
  k_top5<<<dim3(512), dim3(512), 0, stream>>>(xt, xn, cent, cn, t5);
  k_out<<<dim3(512), dim3(512), 0, stream>>>(xt, cent, W, t5, eidx, bias, out);
}